// Round 1
// baseline (3841.237 us; speedup 1.0000x reference)
//
#include <hip/hip_runtime.h>
#include <math.h>

#define NTOK 1024
#define DIM 2048
#define NH 16
#define HDIM 128
#define NE 64
#define NTOP 8
#define FF 1024
#define EPSI 1e-5f
#define ASCALE 0.08838834764831845f

// ---------------- RMSNorm (one block per token row) ----------------
__global__ __launch_bounds__(256) void k_rmsnorm(const float* __restrict__ in,
                                                 const float* __restrict__ w,
                                                 float* __restrict__ out) {
  int row = blockIdx.x, tid = threadIdx.x;
  const float* r = in + (size_t)row * DIM;
  float ss = 0.f;
  for (int i = tid; i < DIM; i += 256) { float v = r[i]; ss += v * v; }
#pragma unroll
  for (int o = 1; o < 64; o <<= 1) ss += __shfl_xor(ss, o, 64);
  __shared__ float red[4];
  if ((tid & 63) == 0) red[tid >> 6] = ss;
  __syncthreads();
  float rstd = rsqrtf((red[0] + red[1] + red[2] + red[3]) / (float)DIM + EPSI);
  float* o_ = out + (size_t)row * DIM;
  for (int i = tid; i < DIM; i += 256) o_[i] = r[i] * rstd * w[i];
}

// ---------------- fp32 tiled GEMM: C[M,N] = A[M,K] @ W[N,K]^T (+R) ----------------
// 64x64 tile, BK=16, 256 threads, 4x4 per thread. LDS transposed for float4 reads.
__global__ __launch_bounds__(256) void k_gemm_bt(const float* __restrict__ A,
                                                 const float* __restrict__ W,
                                                 float* __restrict__ C,
                                                 const float* __restrict__ R,
                                                 int M, int N, int K) {
  __shared__ float As[16][68];
  __shared__ float Bs[16][68];
  int tid = threadIdx.x;
  int tx = tid & 15, ty = tid >> 4;
  int m0 = blockIdx.y * 64, n0 = blockIdx.x * 64;
  int lr = tid >> 2, lc4 = (tid & 3) * 4;
  const float* Arow = A + (size_t)(m0 + lr) * K + lc4;
  const float* Wrow = W + (size_t)(n0 + lr) * K + lc4;
  float acc[4][4] = {};
  for (int k0 = 0; k0 < K; k0 += 16) {
    float4 av = *(const float4*)(Arow + k0);
    float4 wv = *(const float4*)(Wrow + k0);
    __syncthreads();
    As[lc4 + 0][lr] = av.x; As[lc4 + 1][lr] = av.y;
    As[lc4 + 2][lr] = av.z; As[lc4 + 3][lr] = av.w;
    Bs[lc4 + 0][lr] = wv.x; Bs[lc4 + 1][lr] = wv.y;
    Bs[lc4 + 2][lr] = wv.z; Bs[lc4 + 3][lr] = wv.w;
    __syncthreads();
#pragma unroll
    for (int kk = 0; kk < 16; kk++) {
      float4 a4 = *(const float4*)&As[kk][ty * 4];
      float4 b4 = *(const float4*)&Bs[kk][tx * 4];
      float a[4] = {a4.x, a4.y, a4.z, a4.w};
      float b[4] = {b4.x, b4.y, b4.z, b4.w};
#pragma unroll
      for (int i = 0; i < 4; i++)
#pragma unroll
        for (int j = 0; j < 4; j++) acc[i][j] += a[i] * b[j];
    }
  }
#pragma unroll
  for (int i = 0; i < 4; i++) {
    size_t ro = (size_t)(m0 + ty * 4 + i) * N + n0 + tx * 4;
#pragma unroll
    for (int j = 0; j < 4; j++)
      C[ro + j] = acc[i][j] + (R ? R[ro + j] : 0.f);
  }
}

// ---------------- q/k full-D RMSNorm + RoPE + head-transpose; v transpose ----------------
// outputs qr/kr/vr in [H][S][HD] layout
__global__ __launch_bounds__(256) void k_qknorm_rope(
    const float* __restrict__ q, const float* __restrict__ k,
    const float* __restrict__ v, const float* __restrict__ qw,
    const float* __restrict__ kw, float* __restrict__ qr,
    float* __restrict__ kr, float* __restrict__ vr) {
  int s = blockIdx.x, tid = threadIdx.x;
  const float* qrow = q + (size_t)s * DIM;
  const float* krow = k + (size_t)s * DIM;
  const float* vrow = v + (size_t)s * DIM;
  float sq = 0.f, sk = 0.f;
  for (int i = tid; i < DIM; i += 256) {
    float a = qrow[i]; sq += a * a;
    float b = krow[i]; sk += b * b;
  }
#pragma unroll
  for (int o = 1; o < 64; o <<= 1) {
    sq += __shfl_xor(sq, o, 64);
    sk += __shfl_xor(sk, o, 64);
  }
  __shared__ float red[8];
  if ((tid & 63) == 0) { red[tid >> 6] = sq; red[4 + (tid >> 6)] = sk; }
  __syncthreads();
  float rq = rsqrtf((red[0] + red[1] + red[2] + red[3]) / (float)DIM + EPSI);
  float rk = rsqrtf((red[4] + red[5] + red[6] + red[7]) / (float)DIM + EPSI);
  // 16 heads x 64 rotation pairs
  for (int idx = tid; idx < NH * 64; idx += 256) {
    int hh = idx >> 6, i = idx & 63;
    float inv = powf(10000.f, -(float)i / 64.f);
    float ang = (float)s * inv;
    float c = cosf(ang), sn = sinf(ang);
    int b = hh * HDIM + i;
    float q1 = qrow[b] * rq * qw[b];
    float q2 = qrow[b + 64] * rq * qw[b + 64];
    float k1 = krow[b] * rk * kw[b];
    float k2 = krow[b + 64] * rk * kw[b + 64];
    size_t ob = ((size_t)hh * NTOK + s) * HDIM + i;
    qr[ob] = q1 * c - q2 * sn;
    qr[ob + 64] = q2 * c + q1 * sn;
    kr[ob] = k1 * c - k2 * sn;
    kr[ob + 64] = k2 * c + k1 * sn;
  }
  for (int idx = tid; idx < DIM; idx += 256) {
    int hh = idx >> 7, d = idx & 127;
    vr[((size_t)hh * NTOK + s) * HDIM + d] = vrow[idx];
  }
}

// ---------------- causal flash attention, fp32, online softmax ----------------
// block = (q-tile of 64 queries, head). 4 threads per query, 32 dims each.
__global__ __launch_bounds__(256) void k_attn(const float* __restrict__ qr,
                                              const float* __restrict__ kr,
                                              const float* __restrict__ vr,
                                              float* __restrict__ ctx) {
  int h = blockIdx.y, qt = blockIdx.x;
  __shared__ __align__(16) float Ks[64][HDIM];
  __shared__ __align__(16) float Vs[64][HDIM];
  int tid = threadIdx.x;
  int ql = tid >> 2, sub = tid & 3;
  int qg = qt * 64 + ql;
  const float* qrow = qr + ((size_t)h * NTOK + qg) * HDIM + sub * 32;
  float4 q4[8], acc[8];
#pragma unroll
  for (int i = 0; i < 8; i++) {
    q4[i] = *(const float4*)(qrow + i * 4);
    acc[i] = make_float4(0.f, 0.f, 0.f, 0.f);
  }
  float m = -1e30f, l = 0.f;
  for (int kt = 0; kt <= qt; kt++) {
    __syncthreads();
    const float4* kg = (const float4*)(kr + ((size_t)h * NTOK + kt * 64) * HDIM);
    const float4* vg = (const float4*)(vr + ((size_t)h * NTOK + kt * 64) * HDIM);
#pragma unroll
    for (int i = 0; i < 8; i++) {
      int e4 = tid + i * 256;
      ((float4*)Ks)[e4] = kg[e4];
      ((float4*)Vs)[e4] = vg[e4];
    }
    __syncthreads();
    int jmax = min(64, qg - kt * 64 + 1);
    for (int j = 0; j < jmax; j++) {
      const float4* kj = (const float4*)&Ks[j][sub * 32];
      float sc = 0.f;
#pragma unroll
      for (int i = 0; i < 8; i++) {
        float4 kv = kj[i];
        sc += q4[i].x * kv.x + q4[i].y * kv.y + q4[i].z * kv.z + q4[i].w * kv.w;
      }
      sc += __shfl_xor(sc, 1, 64);
      sc += __shfl_xor(sc, 2, 64);
      sc *= ASCALE;
      float mn = fmaxf(m, sc);
      float al = __expf(m - mn);
      float p = __expf(sc - mn);
      l = l * al + p;
      const float4* vj = (const float4*)&Vs[j][sub * 32];
#pragma unroll
      for (int i = 0; i < 8; i++) {
        float4 vv = vj[i];
        acc[i].x = acc[i].x * al + p * vv.x;
        acc[i].y = acc[i].y * al + p * vv.y;
        acc[i].z = acc[i].z * al + p * vv.z;
        acc[i].w = acc[i].w * al + p * vv.w;
      }
      m = mn;
    }
  }
  float invl = 1.f / l;
  float* crow = ctx + (size_t)qg * DIM + h * HDIM + sub * 32;
#pragma unroll
  for (int i = 0; i < 8; i++) {
    float4 o = acc[i];
    o.x *= invl; o.y *= invl; o.z *= invl; o.w *= invl;
    *(float4*)(crow + i * 4) = o;
  }
}

// ---------------- router: logits + softmax + top-8 + expert lists ----------------
__global__ void k_zero_counts(int* counts) {
  if (threadIdx.x < NE) counts[threadIdx.x] = 0;
}

__global__ __launch_bounds__(256) void k_router(const float* __restrict__ h,
                                                const float* __restrict__ rw,
                                                float* __restrict__ topw,
                                                int* __restrict__ lists,
                                                int* __restrict__ counts) {
  int s = blockIdx.x, tid = threadIdx.x;
  int e = tid >> 2, sub = tid & 3;
  const float* hrow = h + (size_t)s * DIM;
  const float* wrow = rw + (size_t)e * DIM;
  float p = 0.f;
  for (int i = sub * 4; i < DIM; i += 16) {
    float4 hv = *(const float4*)(hrow + i);
    float4 wv = *(const float4*)(wrow + i);
    p += hv.x * wv.x + hv.y * wv.y + hv.z * wv.z + hv.w * wv.w;
  }
  p += __shfl_xor(p, 1, 64);
  p += __shfl_xor(p, 2, 64);
  __shared__ float probs[NE];
  if (sub == 0) probs[e] = p;
  __syncthreads();
  if (tid == 0) {
    float mx = -1e30f;
    for (int i = 0; i < NE; i++) mx = fmaxf(mx, probs[i]);
    float sum = 0.f;
    for (int i = 0; i < NE; i++) { probs[i] = __expf(probs[i] - mx); sum += probs[i]; }
    float inv = 1.f / sum;
    for (int kk = 0; kk < NTOP; kk++) {
      float best = -1.f; int bi = 0;
      for (int i = 0; i < NE; i++)
        if (probs[i] > best) { best = probs[i]; bi = i; }
      topw[s * NTOP + kk] = best * inv;
      probs[bi] = -1.f;
      int slot = atomicAdd(&counts[bi], 1);
      lists[bi * NTOK + slot] = s * NTOP + kk;  // store g = s*8+k
    }
  }
}

// ---------------- MoE gate+up fused GEMM (gathered rows) + silu*up ----------------
__global__ __launch_bounds__(256) void k_moe_gate_up(
    const float* __restrict__ h, const float* __restrict__ gate,
    const float* __restrict__ up, const int* __restrict__ lists,
    const int* __restrict__ counts, float* __restrict__ act) {
  int e = blockIdx.z;
  int nt = counts[e];
  int m0 = blockIdx.y * 64;
  if (m0 >= nt) return;
  int n0 = blockIdx.x * 64;
  int tid = threadIdx.x;
  int tx = tid & 15, ty = tid >> 4;
  int lr = tid >> 2, lc4 = (tid & 3) * 4;
  __shared__ float As[16][68], Gs[16][68], Us[16][68];
  int grow = (m0 + lr < nt) ? lists[e * NTOK + m0 + lr] : -1;
  bool avalid = grow >= 0;
  const float* Arow = h + (size_t)(avalid ? (grow >> 3) : 0) * DIM + lc4;
  const float* Grow = gate + ((size_t)e * FF + n0 + lr) * DIM + lc4;
  const float* Urow = up + ((size_t)e * FF + n0 + lr) * DIM + lc4;
  float accg[4][4] = {}, accu[4][4] = {};
  for (int k0 = 0; k0 < DIM; k0 += 16) {
    float4 av = avalid ? *(const float4*)(Arow + k0) : make_float4(0.f, 0.f, 0.f, 0.f);
    float4 gv = *(const float4*)(Grow + k0);
    float4 uv = *(const float4*)(Urow + k0);
    __syncthreads();
    As[lc4 + 0][lr] = av.x; As[lc4 + 1][lr] = av.y;
    As[lc4 + 2][lr] = av.z; As[lc4 + 3][lr] = av.w;
    Gs[lc4 + 0][lr] = gv.x; Gs[lc4 + 1][lr] = gv.y;
    Gs[lc4 + 2][lr] = gv.z; Gs[lc4 + 3][lr] = gv.w;
    Us[lc4 + 0][lr] = uv.x; Us[lc4 + 1][lr] = uv.y;
    Us[lc4 + 2][lr] = uv.z; Us[lc4 + 3][lr] = uv.w;
    __syncthreads();
#pragma unroll
    for (int kk = 0; kk < 16; kk++) {
      float4 a4 = *(const float4*)&As[kk][ty * 4];
      float4 g4 = *(const float4*)&Gs[kk][tx * 4];
      float4 u4 = *(const float4*)&Us[kk][tx * 4];
      float a[4] = {a4.x, a4.y, a4.z, a4.w};
      float g[4] = {g4.x, g4.y, g4.z, g4.w};
      float u[4] = {u4.x, u4.y, u4.z, u4.w};
#pragma unroll
      for (int i = 0; i < 4; i++)
#pragma unroll
        for (int j = 0; j < 4; j++) {
          accg[i][j] += a[i] * g[j];
          accu[i][j] += a[i] * u[j];
        }
    }
  }
#pragma unroll
  for (int i = 0; i < 4; i++) {
    int mrow = m0 + ty * 4 + i;
    if (mrow >= nt) continue;
    int gi = lists[e * NTOK + mrow];
    float* arow = act + (size_t)gi * FF + n0 + tx * 4;
#pragma unroll
    for (int j = 0; j < 4; j++) {
      float gg = accg[i][j], uu = accu[i][j];
      arow[j] = gg / (1.f + __expf(-gg)) * uu;  // silu(g)*u
    }
  }
}

// ---------------- MoE down GEMM (gathered rows) + weighted scatter-add ----------------
__global__ __launch_bounds__(256) void k_moe_down(
    const float* __restrict__ act, const float* __restrict__ down,
    const int* __restrict__ lists, const int* __restrict__ counts,
    const float* __restrict__ topw, float* __restrict__ out) {
  int e = blockIdx.z;
  int nt = counts[e];
  int m0 = blockIdx.y * 64;
  if (m0 >= nt) return;
  int n0 = blockIdx.x * 64;
  int tid = threadIdx.x;
  int tx = tid & 15, ty = tid >> 4;
  int lr = tid >> 2, lc4 = (tid & 3) * 4;
  __shared__ float As[16][68], Ws[16][68];
  int grow = (m0 + lr < nt) ? lists[e * NTOK + m0 + lr] : -1;
  bool avalid = grow >= 0;
  const float* Arow = act + (size_t)(avalid ? grow : 0) * FF + lc4;
  const float* Wrow = down + ((size_t)e * DIM + n0 + lr) * FF + lc4;
  float acc[4][4] = {};
  for (int k0 = 0; k0 < FF; k0 += 16) {
    float4 av = avalid ? *(const float4*)(Arow + k0) : make_float4(0.f, 0.f, 0.f, 0.f);
    float4 wv = *(const float4*)(Wrow + k0);
    __syncthreads();
    As[lc4 + 0][lr] = av.x; As[lc4 + 1][lr] = av.y;
    As[lc4 + 2][lr] = av.z; As[lc4 + 3][lr] = av.w;
    Ws[lc4 + 0][lr] = wv.x; Ws[lc4 + 1][lr] = wv.y;
    Ws[lc4 + 2][lr] = wv.z; Ws[lc4 + 3][lr] = wv.w;
    __syncthreads();
#pragma unroll
    for (int kk = 0; kk < 16; kk++) {
      float4 a4 = *(const float4*)&As[kk][ty * 4];
      float4 b4 = *(const float4*)&Ws[kk][tx * 4];
      float a[4] = {a4.x, a4.y, a4.z, a4.w};
      float b[4] = {b4.x, b4.y, b4.z, b4.w};
#pragma unroll
      for (int i = 0; i < 4; i++)
#pragma unroll
        for (int j = 0; j < 4; j++) acc[i][j] += a[i] * b[j];
    }
  }
#pragma unroll
  for (int i = 0; i < 4; i++) {
    int mrow = m0 + ty * 4 + i;
    if (mrow >= nt) continue;
    int gi = lists[e * NTOK + mrow];
    int s = gi >> 3;
    float wgt = topw[gi];
    float* orow = out + (size_t)s * DIM + n0 + tx * 4;
#pragma unroll
    for (int j = 0; j < 4; j++) atomicAdd(&orow[j], wgt * acc[i][j]);
  }
}

extern "C" void kernel_launch(void* const* d_in, const int* in_sizes, int n_in,
                              void* d_out, int out_size, void* d_ws, size_t ws_size,
                              hipStream_t stream) {
  const float* x   = (const float*)d_in[0];
  const float* iln = (const float*)d_in[1];
  const float* qw  = (const float*)d_in[2];
  const float* qnw = (const float*)d_in[3];
  const float* kw  = (const float*)d_in[4];
  const float* knw = (const float*)d_in[5];
  const float* vw  = (const float*)d_in[6];
  const float* ow  = (const float*)d_in[7];
  const float* pln = (const float*)d_in[8];
  const float* rw  = (const float*)d_in[9];
  const float* gw  = (const float*)d_in[10];
  const float* uw  = (const float*)d_in[11];
  const float* dw  = (const float*)d_in[12];
  float* out = (float*)d_out;
  float* ws = (float*)d_ws;

  const size_t M2 = (size_t)NTOK * DIM;  // 2M floats
  // ws layout (aliased across phases; needs ~57 MB):
  float* xn = ws + 0 * M2;  // also reused as ctx
  float* qb = ws + 1 * M2;  // also reused as h (post-LN)
  float* kb = ws + 2 * M2;
  float* vb = ws + 3 * M2;
  float* qr = ws + 4 * M2;
  float* kr = ws + 5 * M2;
  float* vr = ws + 6 * M2;
  float* act = ws + 3 * M2;           // 4*M2 floats, reuses vb/qr/kr/vr after attention
  float* topw = ws + 7 * M2;          // 8192 floats
  int* lists = (int*)(topw + NTOK * NTOP);  // 64*1024 ints
  int* counts = lists + NE * NTOK;          // 64 ints

  dim3 g1(DIM / 64, NTOK / 64);  // (32,16)

  // 1. input RMSNorm
  k_rmsnorm<<<NTOK, 256, 0, stream>>>(x, iln, xn);
  // 2-4. Q,K,V projections
  k_gemm_bt<<<g1, 256, 0, stream>>>(xn, qw, qb, nullptr, NTOK, DIM, DIM);
  k_gemm_bt<<<g1, 256, 0, stream>>>(xn, kw, kb, nullptr, NTOK, DIM, DIM);
  k_gemm_bt<<<g1, 256, 0, stream>>>(xn, vw, vb, nullptr, NTOK, DIM, DIM);
  // 5. q/k norm + RoPE + head transpose, v transpose
  k_qknorm_rope<<<NTOK, 256, 0, stream>>>(qb, kb, vb, qnw, knw, qr, kr, vr);
  // 6. causal attention -> ctx (into xn, [s][h*128+d] layout)
  k_attn<<<dim3(NTOK / 64, NH), 256, 0, stream>>>(qr, kr, vr, xn);
  // 7. O projection + residual -> out holds x_res
  k_gemm_bt<<<g1, 256, 0, stream>>>(xn, ow, out, x, NTOK, DIM, DIM);
  // 8. post-attention RMSNorm -> h (into qb)
  k_rmsnorm<<<NTOK, 256, 0, stream>>>(out, pln, qb);
  // 9. routing
  k_zero_counts<<<1, 64, 0, stream>>>(counts);
  k_router<<<NTOK, 256, 0, stream>>>(qb, rw, topw, lists, counts);
  // 10. sparse MoE: gate/up + silu*up -> act
  k_moe_gate_up<<<dim3(FF / 64, NTOK / 64, NE), 256, 0, stream>>>(qb, gw, uw, lists, counts, act);
  // 11. down proj, weighted scatter-add into out (out += moe)
  k_moe_down<<<dim3(DIM / 64, NTOK / 64, NE), 256, 0, stream>>>(act, dw, lists, counts, topw, out);
}